// Round 2
// baseline (920.144 us; speedup 1.0000x reference)
//
#include <hip/hip_runtime.h>
#include <stdint.h>

#define NNODES 20000
#define NEDGES 160000
#define NPAD   20096   // 157 * 128

typedef float f32x4 __attribute__((ext_vector_type(4)));
typedef float f32x2 __attribute__((ext_vector_type(2)));
typedef short s16x8 __attribute__((ext_vector_type(8)));

__device__ __forceinline__ float b2f(unsigned short b) {
    unsigned int u = ((unsigned int)b) << 16;
    return __builtin_bit_cast(float, u);
}
__device__ __forceinline__ unsigned short f2b(float f) {
    unsigned int u = __builtin_bit_cast(unsigned int, f);
    unsigned int r = (u + 0x7FFFu + ((u >> 16) & 1u)) >> 16;
    return (unsigned short)r;
}
// unpack 2 bf16 (packed in a dword) -> float2
__device__ __forceinline__ f32x2 unpack2(unsigned int u) {
    f32x2 r;
    r.x = __builtin_bit_cast(float, u << 16);
    r.y = __builtin_bit_cast(float, u & 0xFFFF0000u);
    return r;
}
// packed fp32 math (VOP3P) — 2 FMAs / 1 instruction
__device__ __forceinline__ f32x2 pk_mul(f32x2 a, f32x2 b) {
    f32x2 d;
    asm("v_pk_mul_f32 %0, %1, %2" : "=v"(d) : "v"(a), "v"(b));
    return d;
}
__device__ __forceinline__ f32x2 pk_fma(f32x2 a, f32x2 b, f32x2 c) {
    f32x2 d;
    asm("v_pk_fma_f32 %0, %1, %2, %3" : "=v"(d) : "v"(a), "v"(b), "v"(c));
    return d;
}

// ---- GEMM: C[M,N] = A[M,K](bf16) @ BT[N,K]^T(bf16); C fp32 or bf16 ----
__global__ __launch_bounds__(256) void gemm_bt_kernel(
    const unsigned short* __restrict__ A,
    const unsigned short* __restrict__ BT,
    float* __restrict__ Cf,
    unsigned short* __restrict__ Cb,
    int M, int N, int K,
    const float* __restrict__ bias)
{
    __shared__ unsigned short As[128 * 32];
    __shared__ unsigned short Bs[128 * 32];
    const int tid  = threadIdx.x;
    const int wid  = tid >> 6;
    const int lane = tid & 63;
    const int bm = blockIdx.x * 128;
    const int bn = blockIdx.y * 128;
    const int wm = (wid & 1) * 64;
    const int wn = (wid >> 1) * 64;

    f32x4 acc[4][4];
#pragma unroll
    for (int i = 0; i < 4; i++)
#pragma unroll
        for (int j = 0; j < 4; j++) acc[i][j] = {0.f, 0.f, 0.f, 0.f};

    for (int k0 = 0; k0 < K; k0 += 32) {
#pragma unroll
        for (int r = 0; r < 2; r++) {
            int flat = r * 256 + tid;
            int row  = flat >> 2;
            int part = flat & 3;
            const unsigned short* ga = A  + (size_t)(bm + row) * K + k0 + part * 8;
            const unsigned short* gb = BT + (size_t)(bn + row) * K + k0 + part * 8;
            __builtin_amdgcn_global_load_lds(
                (const __attribute__((address_space(1))) unsigned int*)ga,
                (__attribute__((address_space(3))) unsigned int*)&As[flat * 8], 16, 0, 0);
            __builtin_amdgcn_global_load_lds(
                (const __attribute__((address_space(1))) unsigned int*)gb,
                (__attribute__((address_space(3))) unsigned int*)&Bs[flat * 8], 16, 0, 0);
        }
        __syncthreads();

        const int kq = (lane >> 4) * 8;
        const int rl = lane & 15;
        s16x8 af[4], bfr[4];
#pragma unroll
        for (int mi = 0; mi < 4; mi++)
            af[mi] = *(const s16x8*)&As[(wm + mi * 16 + rl) * 32 + kq];
#pragma unroll
        for (int ni = 0; ni < 4; ni++)
            bfr[ni] = *(const s16x8*)&Bs[(wn + ni * 16 + rl) * 32 + kq];
#pragma unroll
        for (int mi = 0; mi < 4; mi++)
#pragma unroll
            for (int ni = 0; ni < 4; ni++)
                acc[mi][ni] = __builtin_amdgcn_mfma_f32_16x16x32_bf16(
                    af[mi], bfr[ni], acc[mi][ni], 0, 0, 0);
        __syncthreads();
    }

    const int cl = lane & 15;
    const int rq = (lane >> 4) * 4;
#pragma unroll
    for (int mi = 0; mi < 4; mi++)
#pragma unroll
        for (int ni = 0; ni < 4; ni++)
#pragma unroll
            for (int r = 0; r < 4; r++) {
                int row = bm + wm + mi * 16 + rq + r;
                int col = bn + wn + ni * 16 + cl;
                float v = acc[mi][ni][r];
                if (Cb) {
                    if (bias) v = fmaxf(v + bias[col], 0.f);
                    Cb[(size_t)row * N + col] = f2b(v);
                } else {
                    Cf[(size_t)row * N + col] = v;
                }
            }
}

// ---------------- CSR build ----------------
__global__ void count_kernel(const int* __restrict__ ei, int* __restrict__ counts) {
    int e = blockIdx.x * blockDim.x + threadIdx.x;
    if (e < NEDGES) atomicAdd(&counts[ei[NEDGES + e]], 1);
}

__global__ __launch_bounds__(1024) void scan_kernel(const int* __restrict__ counts,
                                                    int* __restrict__ row_ptr)
{
    __shared__ int sdata[1024];
    const int t = threadIdx.x;
    int vals[20];
    const int base = t * 20;
    int lsum = 0;
#pragma unroll
    for (int j = 0; j < 20; j++) {
        int idx = base + j;
        int v = (idx < NNODES) ? counts[idx] : 0;
        vals[j] = v; lsum += v;
    }
    sdata[t] = lsum;
    __syncthreads();
    for (int off = 1; off < 1024; off <<= 1) {
        int v = (t >= off) ? sdata[t - off] : 0;
        __syncthreads();
        sdata[t] += v;
        __syncthreads();
    }
    int run = sdata[t] - lsum;
#pragma unroll
    for (int j = 0; j < 20; j++) {
        int idx = base + j;
        if (idx < NNODES) row_ptr[idx] = run;
        run += vals[j];
    }
    if (t == 1023) row_ptr[NNODES] = sdata[1023];
}

__global__ void fill_kernel(const int* __restrict__ ei,
                            const int* __restrict__ row_ptr,
                            int* __restrict__ cursor,
                            int2* __restrict__ csr)   // {src, eid}
{
    int e = blockIdx.x * blockDim.x + threadIdx.x;
    if (e >= NEDGES) return;
    int dst = ei[NEDGES + e];
    int p = row_ptr[dst] + atomicAdd(&cursor[dst], 1);
    csr[p] = make_int2(ei[e], e);
}

__global__ void dinv_kernel(const int* __restrict__ row_ptr, float* __restrict__ dinv) {
    int i = blockIdx.x * blockDim.x + threadIdx.x;
    if (i < NNODES) {
        int deg = row_ptr[i + 1] - row_ptr[i] + 1;   // + self loop
        dinv[i] = rsqrtf((float)deg);
    }
}

// ---------------- packing ----------------
__global__ void pad_copy_kernel(const float* __restrict__ src,
                                unsigned short* __restrict__ dst,
                                int valid_rows, int cols, long total)
{
    long idx = (long)blockIdx.x * blockDim.x + threadIdx.x;
    if (idx >= total) return;
    int n = (int)(idx / cols);
    dst[idx] = (n < valid_rows) ? f2b(src[idx]) : (unsigned short)0;
}

// Interleaved P column layout (groups of 4 columns per channel pair):
//   cols [0,1024):   group cp: [f_dst[2cp], f_dst[2cp+1], s_dst[2cp], s_dst[2cp+1]]
//   cols [1024,2048): same for src projections
// -> per-edge gather reads ONE dwordx2 instead of two dwords 2KB apart.
__global__ void pack_cgw_kernel(const float* __restrict__ Wf,
                                const float* __restrict__ Ws,
                                unsigned short* __restrict__ out)
{
    int idx = blockIdx.x * blockDim.x + threadIdx.x;
    if (idx >= 2048 * 512) return;
    int j = idx >> 9;          // output column (wpack row) 0..2047
    int k = idx & 511;         // K index
    int half = (j >= 1024);    // 0 = dst block, 1 = src block
    int jj = j & 1023;
    int c  = (jj >> 2) * 2 + (jj & 1);   // channel
    int fs = (jj >> 1) & 1;              // 0 = f, 1 = s
    const float* W = fs ? Ws : Wf;
    float v = W[(size_t)(half ? 512 + k : k) * 512 + c];
    out[idx] = f2b(v);
}

__global__ void pack_t_kernel(const float* __restrict__ W,
                              unsigned short* __restrict__ WT,
                              int K, int Nout)
{
    long idx = (long)blockIdx.x * blockDim.x + threadIdx.x;
    if (idx >= (long)K * Nout) return;
    int j = (int)(idx / K);
    int k = (int)(idx % K);
    WT[idx] = f2b(W[(size_t)k * Nout + j]);
}

// ---------------- CGConv gather ----------------
// Per-thread channels (c0, c0+1). W_e held TRULY register-resident (asm opacity
// barrier prevents rematerialization — round-1 kernel showed VGPR=48, i.e. the
// compiler was re-loading weights from L1 every edge: that was the bottleneck).
// k-pair-packed weights so the 16-dim edge FMA runs as v_pk_fma_f32.
// Depth-2 software pipeline (A/B register sets), wave-uniform CSR/edge-attr
// addressing via readfirstlane.
#define CG_NPB 4

#define CG_LOAD(Ea, Eb, Ec, Ed, Eq, idx) do {                                  \
    int2 se_ = csr[idx];                                                       \
    int sx_ = __builtin_amdgcn_readfirstlane(se_.x);                           \
    int sy_ = __builtin_amdgcn_readfirstlane(se_.y);                           \
    const f32x4* ep_ = (const f32x4*)(ea + (size_t)sy_ * 16);                  \
    Ea = ep_[0]; Eb = ep_[1]; Ec = ep_[2]; Ed = ep_[3];                        \
    Eq = *(const uint2*)(P + (size_t)sx_ * 2048 + 1024 + c0 * 2);              \
} while (0)

#define CG_COMP(Ea, Eb, Ec, Ed, Eq) do {                                       \
    f32x2 ee[8];                                                               \
    ee[0] = __builtin_shufflevector(Ea, Ea, 0, 1);                             \
    ee[1] = __builtin_shufflevector(Ea, Ea, 2, 3);                             \
    ee[2] = __builtin_shufflevector(Eb, Eb, 0, 1);                             \
    ee[3] = __builtin_shufflevector(Eb, Eb, 2, 3);                             \
    ee[4] = __builtin_shufflevector(Ec, Ec, 0, 1);                             \
    ee[5] = __builtin_shufflevector(Ec, Ec, 2, 3);                             \
    ee[6] = __builtin_shufflevector(Ed, Ed, 0, 1);                             \
    ee[7] = __builtin_shufflevector(Ed, Ed, 2, 3);                             \
    f32x2 fa_ = pk_mul(ee[0], wfA[0]);                                         \
    f32x2 fb_ = pk_mul(ee[0], wfB[0]);                                         \
    f32x2 sa_ = pk_mul(ee[0], wsA[0]);                                         \
    f32x2 sb_ = pk_mul(ee[0], wsB[0]);                                         \
    _Pragma("unroll")                                                          \
    for (int j_ = 1; j_ < 8; j_++) {                                           \
        fa_ = pk_fma(ee[j_], wfA[j_], fa_);                                    \
        fb_ = pk_fma(ee[j_], wfB[j_], fb_);                                    \
        sa_ = pk_fma(ee[j_], wsA[j_], sa_);                                    \
        sb_ = pk_fma(ee[j_], wsB[j_], sb_);                                    \
    }                                                                          \
    f32x2 pf_ = unpack2(Eq.x);                                                 \
    f32x2 ps_ = unpack2(Eq.y);                                                 \
    float f0_ = (fa_.x + fa_.y) + (baseF.x + pf_.x);                           \
    float f1_ = (fb_.x + fb_.y) + (baseF.y + pf_.y);                           \
    float s0_ = (sa_.x + sa_.y) + (baseS.x + ps_.x);                           \
    float s1_ = (sb_.x + sb_.y) + (baseS.y + ps_.y);                           \
    float sp0_ = __logf(1.f + __expf(s0_));                                    \
    float sp1_ = __logf(1.f + __expf(s1_));                                    \
    float sg0_ = __builtin_amdgcn_rcpf(1.f + __expf(-f0_));                    \
    float sg1_ = __builtin_amdgcn_rcpf(1.f + __expf(-f1_));                    \
    acc.x = fmaf(sp0_, sg0_, acc.x);                                           \
    acc.y = fmaf(sp1_, sg1_, acc.y);                                           \
} while (0)

__global__ __launch_bounds__(256, 1) void cg_gather_kernel(
    const unsigned short* __restrict__ P,
    const int* __restrict__ row_ptr,
    const int2* __restrict__ csr,
    const float* __restrict__ ea,
    const float* __restrict__ Wf,   // [1040,512], rows 1024.. = W_e
    const float* __restrict__ Ws,
    const float* __restrict__ bfv,
    const float* __restrict__ bsv,
    const float* __restrict__ g,
    const float* __restrict__ be,
    const float* __restrict__ xresf,          // fp32 [NNODES,512] or null
    const unsigned short* __restrict__ xresb, // bf16 [NPAD,512] or null
    unsigned short* __restrict__ hout)
{
    const int tid = threadIdx.x;
    const int c0  = tid * 2;
    const int nbase = blockIdx.x * CG_NPB;

    // k-pair-packed register-resident W_e for channels c0 and c0+1:
    //   wfA[j] = (Wf_e[2j][c0],   Wf_e[2j+1][c0])
    //   wfB[j] = (Wf_e[2j][c0+1], Wf_e[2j+1][c0+1])   (same for Ws)
    f32x2 wfA[8], wfB[8], wsA[8], wsB[8];
#pragma unroll
    for (int j = 0; j < 8; j++) {
        const size_t r0 = (size_t)(1024 + 2 * j) * 512;
        const size_t r1 = r0 + 512;
        f32x2 f0 = *(const f32x2*)&Wf[r0 + c0];
        f32x2 f1 = *(const f32x2*)&Wf[r1 + c0];
        f32x2 s0 = *(const f32x2*)&Ws[r0 + c0];
        f32x2 s1 = *(const f32x2*)&Ws[r1 + c0];
        wfA[j] = f32x2{f0.x, f1.x};
        wfB[j] = f32x2{f0.y, f1.y};
        wsA[j] = f32x2{s0.x, s1.x};
        wsB[j] = f32x2{s0.y, s1.y};
    }
    // opacity barrier: forbids rematerialization -> weights stay in VGPRs
#pragma unroll
    for (int j = 0; j < 8; j++)
        asm volatile("" : "+v"(wfA[j]), "+v"(wfB[j]), "+v"(wsA[j]), "+v"(wsB[j]));

    const f32x2 bfx = *(const f32x2*)&bfv[c0];
    const f32x2 bsx = *(const f32x2*)&bsv[c0];
    const f32x2 gv  = *(const f32x2*)&g[c0];
    const f32x2 bev = *(const f32x2*)&be[c0];
    const float rs = rsqrtf(1.f + 1e-5f);

    for (int n = nbase; n < nbase + CG_NPB; n++) {
        if (n >= NNODES) {
            *(unsigned int*)&hout[(size_t)n * 512 + c0] = 0;
            continue;
        }
        const unsigned short* Pd = P + (size_t)n * 2048;
        const uint2 qb = *(const uint2*)(Pd + c0 * 2);
        const f32x2 baseF = unpack2(qb.x) + bfx;
        const f32x2 baseS = unpack2(qb.y) + bsx;

        f32x2 acc = {0.f, 0.f};
        const int i0 = row_ptr[n], i1 = row_ptr[n + 1];

        if (i0 < i1) {
            f32x4 Aa, Ab, Ac, Ad; uint2 Aq;
            f32x4 Ba, Bb, Bc, Bd; uint2 Bq;
            CG_LOAD(Aa, Ab, Ac, Ad, Aq, i0);
            if (i0 + 1 < i1) CG_LOAD(Ba, Bb, Bc, Bd, Bq, i0 + 1);
            int i = i0;
            while (true) {
                CG_COMP(Aa, Ab, Ac, Ad, Aq);
                if (i + 2 < i1) CG_LOAD(Aa, Ab, Ac, Ad, Aq, i + 2);
                if (i + 1 >= i1) break;
                CG_COMP(Ba, Bb, Bc, Bd, Bq);
                if (i + 3 < i1) CG_LOAD(Ba, Bb, Bc, Bd, Bq, i + 3);
                i += 2;
                if (i >= i1) break;
            }
        }
        // fused BN(eval) + residual + ReLU
        f32x2 res;
        if (xresf) {
            res = *(const f32x2*)&xresf[(size_t)n * 512 + c0];
        } else {
            res = unpack2(*(const unsigned int*)&xresb[(size_t)n * 512 + c0]);
        }
        float v0 = fmaxf(acc.x * (gv.x * rs) + bev.x + res.x, 0.f);
        float v1 = fmaxf(acc.y * (gv.y * rs) + bev.y + res.y, 0.f);
        unsigned int packed = (unsigned int)f2b(v0) | ((unsigned int)f2b(v1) << 16);
        *(unsigned int*)&hout[(size_t)n * 512 + c0] = packed;
    }
}

// ---------------- GCN gather (2 nodes/block, 2 ch/thread, scalarized src) ----------------
__global__ __launch_bounds__(256) void gcn_gather_kernel(
    const unsigned short* __restrict__ pre,   // bf16 [NPAD,256]
    const int* __restrict__ row_ptr,
    const int2* __restrict__ csr,
    const float* __restrict__ dinv,
    const float* __restrict__ b,
    unsigned short* __restrict__ hout,  // bf16 [NPAD,256]
    float* __restrict__ doutf)          // fp32 [NNODES,256] or null
{
    const int tid = threadIdx.x;
    const int n = blockIdx.x * 2 + (tid >> 7);   // waves 0-1 -> node A, 2-3 -> node B
    const int c = (tid & 127) * 2;
    if (n >= NNODES) {
        if (n < NPAD) *(unsigned int*)&hout[(size_t)n * 256 + c] = 0;
        return;
    }
    const float din = dinv[n];
    f32x2 acc = {0.f, 0.f};
    const int i0 = row_ptr[n], i1 = row_ptr[n + 1];
    if (i0 < i1) {
        int sx = __builtin_amdgcn_readfirstlane(csr[i0].x);
        float dv = dinv[sx];
        unsigned int pv = *(const unsigned int*)&pre[(size_t)sx * 256 + c];
        for (int i = i0; i < i1; i++) {
            float cdv = dv; unsigned int cpv = pv;
            if (i + 1 < i1) {
                int sx2 = __builtin_amdgcn_readfirstlane(csr[i + 1].x);
                dv = dinv[sx2];
                pv = *(const unsigned int*)&pre[(size_t)sx2 * 256 + c];
            }
            f32x2 p = unpack2(cpv);
            acc.x = fmaf(cdv, p.x, acc.x);
            acc.y = fmaf(cdv, p.y, acc.y);
        }
    }
    f32x2 self = unpack2(*(const unsigned int*)&pre[(size_t)n * 256 + c]);
    const f32x2 bv = *(const f32x2*)&b[c];
    float v0 = fmaxf(fmaf(acc.x, din, din * din * self.x) + bv.x, 0.f);
    float v1 = fmaxf(fmaf(acc.y, din, din * din * self.y) + bv.y, 0.f);
    *(unsigned int*)&hout[(size_t)n * 256 + c] =
        (unsigned int)f2b(v0) | ((unsigned int)f2b(v1) << 16);
    if (doutf) {
        f32x2 vv = {v0, v1};
        *(f32x2*)&doutf[(size_t)n * 256 + c] = vv;
    }
}

// ---------------- MLP ----------------
__global__ void build_zc_kernel(const unsigned short* __restrict__ h4,
                                const float* __restrict__ goal,
                                unsigned short* __restrict__ zc)
{
    long idx = (long)blockIdx.x * blockDim.x + threadIdx.x;
    if (idx >= (long)NPAD * 768) return;
    int n = (int)(idx / 768);
    int c = (int)(idx % 768);
    unsigned short v = 0;
    if (n < NNODES)
        v = (c < 256) ? h4[(size_t)n * 256 + c]
                      : f2b(goal[(size_t)n * 512 + (c - 256)]);
    zc[idx] = v;
}

__global__ __launch_bounds__(256) void final_dot_kernel(
    const unsigned short* __restrict__ t,
    const float* __restrict__ Wd2,
    const float* __restrict__ bd2,
    float* __restrict__ pred)
{
    const int lane = threadIdx.x & 63;
    const int wid  = threadIdx.x >> 6;
    float w[8];
#pragma unroll
    for (int i = 0; i < 8; i++) w[i] = Wd2[lane * 8 + i];
    const float bd = bd2[0];
    for (int n = blockIdx.x * 4 + wid; n < NNODES; n += gridDim.x * 4) {
        const unsigned short* tp = t + (size_t)n * 512 + lane * 8;
        float s = 0.f;
#pragma unroll
        for (int i = 0; i < 8; i++) s = fmaf(b2f(tp[i]), w[i], s);
#pragma unroll
        for (int off = 32; off; off >>= 1) s += __shfl_xor(s, off, 64);
        if (lane == 0) pred[n] = s + bd;
    }
}

// ---------------- launcher ----------------
extern "C" void kernel_launch(void* const* d_in, const int* in_sizes, int n_in,
                              void* d_out, int out_size, void* d_ws, size_t ws_size,
                              hipStream_t stream)
{
    (void)in_sizes; (void)n_in; (void)out_size; (void)ws_size;
    const float* x    = (const float*)d_in[0];
    const int*   ei   = (const int*)d_in[1];
    const float* ea   = (const float*)d_in[2];
    const float* goal = (const float*)d_in[3];
    const float* Wf1  = (const float*)d_in[4];
    const float* bf1  = (const float*)d_in[5];
    const float* Ws1  = (const float*)d_in[6];
    const float* bs1  = (const float*)d_in[7];
    const float* g1   = (const float*)d_in[8];
    const float* be1  = (const float*)d_in[9];
    const float* Wf2  = (const float*)d_in[10];
    const float* bf2  = (const float*)d_in[11];
    const float* Ws2  = (const float*)d_in[12];
    const float* bs2  = (const float*)d_in[13];
    const float* g2   = (const float*)d_in[14];
    const float* be2  = (const float*)d_in[15];
    const float* W3   = (const float*)d_in[16];
    const float* b3   = (const float*)d_in[17];
    const float* W4   = (const float*)d_in[18];
    const float* b4   = (const float*)d_in[19];
    const float* Wd1  = (const float*)d_in[20];
    const float* bd1  = (const float*)d_in[21];
    const float* Wd2  = (const float*)d_in[22];
    const float* bd2  = (const float*)d_in[23];
    float* outp = (float*)d_out;   // fp32: [0..N) pred, [N..N+N*256) h

    char* ws = (char*)d_ws;
    size_t off = 0;
    auto alloc = [&](size_t bytes) -> char* {
        char* p = ws + off;
        off += (bytes + 255) & ~(size_t)255;
        return p;
    };
    unsigned short* P     = (unsigned short*)alloc((size_t)NPAD * 2048 * 2); // later zc + tb
    unsigned short* bufA  = (unsigned short*)alloc((size_t)NPAD * 512 * 2);  // xpad / h2 / h4
    unsigned short* bufB  = (unsigned short*)alloc((size_t)NPAD * 512 * 2);  // h1 / pre_b
    unsigned short* bufC  = (unsigned short*)alloc((size_t)NPAD * 512 * 2);  // h3
    unsigned short* wpack = (unsigned short*)alloc((size_t)2048 * 512 * 2);
    int*            counts  = (int*)alloc((size_t)NNODES * 4);
    int*            row_ptr = (int*)alloc((size_t)(NNODES + 1) * 4);
    int2*           csr     = (int2*)alloc((size_t)NEDGES * 8);
    float*          dinv    = (float*)alloc((size_t)NNODES * 4);

    unsigned short* xpad  = bufA;
    unsigned short* h1    = bufB;
    unsigned short* h2    = bufA;
    unsigned short* pre_b = bufB;
    unsigned short* h3    = bufC;
    unsigned short* h4    = bufA;
    unsigned short* zc    = P;
    unsigned short* tb    = P + (size_t)NPAD * 1024;

    const int B = 256;

    // ---- CSR build (by destination) + dinv ----
    hipMemsetAsync(counts, 0, (size_t)NNODES * 4, stream);
    count_kernel<<<(NEDGES + B - 1) / B, B, 0, stream>>>(ei, counts);
    scan_kernel<<<1, 1024, 0, stream>>>(counts, row_ptr);
    hipMemsetAsync(counts, 0, (size_t)NNODES * 4, stream);
    fill_kernel<<<(NEDGES + B - 1) / B, B, 0, stream>>>(ei, row_ptr, counts, csr);
    dinv_kernel<<<(NNODES + B - 1) / B, B, 0, stream>>>(row_ptr, dinv);

    {
        long tot = (long)NPAD * 512;
        pad_copy_kernel<<<(unsigned)((tot + B - 1) / B), B, 0, stream>>>(x, xpad, NNODES, 512, tot);
    }

    dim3 gBig(NPAD / 128, 2048 / 128);

    // ---- CGConv layer 1 ----
    pack_cgw_kernel<<<(2048 * 512 + B - 1) / B, B, 0, stream>>>(Wf1, Ws1, wpack);
    gemm_bt_kernel<<<gBig, B, 0, stream>>>(xpad, wpack, nullptr, P, NPAD, 2048, 512, nullptr);
    cg_gather_kernel<<<NPAD / CG_NPB, B, 0, stream>>>(P, row_ptr, csr, ea,
                                                      Wf1, Ws1, bf1, bs1, g1, be1,
                                                      x, nullptr, h1);

    // ---- CGConv layer 2 ----
    pack_cgw_kernel<<<(2048 * 512 + B - 1) / B, B, 0, stream>>>(Wf2, Ws2, wpack);
    gemm_bt_kernel<<<gBig, B, 0, stream>>>(h1, wpack, nullptr, P, NPAD, 2048, 512, nullptr);
    cg_gather_kernel<<<NPAD / CG_NPB, B, 0, stream>>>(P, row_ptr, csr, ea,
                                                      Wf2, Ws2, bf2, bs2, g2, be2,
                                                      nullptr, h1, h2);

    // ---- GCN layer 3 ----
    pack_t_kernel<<<(256 * 512 + B - 1) / B, B, 0, stream>>>(W3, wpack, 512, 256);
    gemm_bt_kernel<<<dim3(NPAD / 128, 2), B, 0, stream>>>(h2, wpack, nullptr, pre_b, NPAD, 256, 512, nullptr);
    gcn_gather_kernel<<<NPAD / 2, B, 0, stream>>>(pre_b, row_ptr, csr, dinv, b3, h3, (float*)nullptr);

    // ---- GCN layer 4 ----
    pack_t_kernel<<<(256 * 256 + B - 1) / B, B, 0, stream>>>(W4, wpack, 256, 256);
    gemm_bt_kernel<<<dim3(NPAD / 128, 2), B, 0, stream>>>(h3, wpack, nullptr, pre_b, NPAD, 256, 256, nullptr);
    gcn_gather_kernel<<<NPAD / 2, B, 0, stream>>>(pre_b, row_ptr, csr, dinv, b4, h4, outp + NNODES);

    // ---- distance MLP (bias+ReLU fused into GEMM epilogue) ----
    build_zc_kernel<<<(unsigned)(((long)NPAD * 768 + B - 1) / B), B, 0, stream>>>(h4, goal, zc);
    pack_t_kernel<<<(512 * 768 + B - 1) / B, B, 0, stream>>>(Wd1, wpack, 768, 512);
    gemm_bt_kernel<<<dim3(NPAD / 128, 4), B, 0, stream>>>(zc, wpack, nullptr, tb, NPAD, 512, 768, bd1);
    final_dot_kernel<<<512, B, 0, stream>>>(tb, Wd2, bd2, outp);
}

// Round 3
// 821.436 us; speedup vs baseline: 1.1202x; 1.1202x over previous
//
#include <hip/hip_runtime.h>
#include <stdint.h>

#define NNODES 20000
#define NEDGES 160000
#define NPAD   20096   // 157 * 128

typedef float f32x4 __attribute__((ext_vector_type(4)));
typedef float f32x2 __attribute__((ext_vector_type(2)));
typedef short s16x8 __attribute__((ext_vector_type(8)));
typedef unsigned int u32x4 __attribute__((ext_vector_type(4)));
typedef _Float16 h16x2 __attribute__((ext_vector_type(2)));

__device__ __forceinline__ float b2f(unsigned short b) {
    unsigned int u = ((unsigned int)b) << 16;
    return __builtin_bit_cast(float, u);
}
__device__ __forceinline__ unsigned short f2b(float f) {
    unsigned int u = __builtin_bit_cast(unsigned int, f);
    unsigned int r = (u + 0x7FFFu + ((u >> 16) & 1u)) >> 16;
    return (unsigned short)r;
}
// unpack 2 bf16 (packed in a dword) -> float2
__device__ __forceinline__ f32x2 unpack2(unsigned int u) {
    f32x2 r;
    r.x = __builtin_bit_cast(float, u << 16);
    r.y = __builtin_bit_cast(float, u & 0xFFFF0000u);
    return r;
}
// pack two fp32 -> fp16 pair in a dword
__device__ __forceinline__ unsigned int packh2(float a, float b) {
    h16x2 h = { (_Float16)a, (_Float16)b };
    return __builtin_bit_cast(unsigned int, h);
}
// fp16-pair dot with fp32 accumulate: one v_dot2_f32_f16
__device__ __forceinline__ float dot2h(unsigned int a, unsigned int b, float c) {
#if __has_builtin(__builtin_amdgcn_fdot2)
    return __builtin_amdgcn_fdot2(__builtin_bit_cast(h16x2, a),
                                  __builtin_bit_cast(h16x2, b), c, false);
#else
    float d;
    asm("v_dot2_f32_f16 %0, %1, %2, %3" : "=v"(d) : "v"(a), "v"(b), "v"(c));
    return d;
#endif
}

// ---- GEMM: C[M,N] = A[M,K](bf16) @ BT[N,K]^T(bf16); C fp32 or bf16 ----
__global__ __launch_bounds__(256) void gemm_bt_kernel(
    const unsigned short* __restrict__ A,
    const unsigned short* __restrict__ BT,
    float* __restrict__ Cf,
    unsigned short* __restrict__ Cb,
    int M, int N, int K,
    const float* __restrict__ bias)
{
    __shared__ unsigned short As[128 * 32];
    __shared__ unsigned short Bs[128 * 32];
    const int tid  = threadIdx.x;
    const int wid  = tid >> 6;
    const int lane = tid & 63;
    const int bm = blockIdx.x * 128;
    const int bn = blockIdx.y * 128;
    const int wm = (wid & 1) * 64;
    const int wn = (wid >> 1) * 64;

    f32x4 acc[4][4];
#pragma unroll
    for (int i = 0; i < 4; i++)
#pragma unroll
        for (int j = 0; j < 4; j++) acc[i][j] = {0.f, 0.f, 0.f, 0.f};

    for (int k0 = 0; k0 < K; k0 += 32) {
#pragma unroll
        for (int r = 0; r < 2; r++) {
            int flat = r * 256 + tid;
            int row  = flat >> 2;
            int part = flat & 3;
            const unsigned short* ga = A  + (size_t)(bm + row) * K + k0 + part * 8;
            const unsigned short* gb = BT + (size_t)(bn + row) * K + k0 + part * 8;
            __builtin_amdgcn_global_load_lds(
                (const __attribute__((address_space(1))) unsigned int*)ga,
                (__attribute__((address_space(3))) unsigned int*)&As[flat * 8], 16, 0, 0);
            __builtin_amdgcn_global_load_lds(
                (const __attribute__((address_space(1))) unsigned int*)gb,
                (__attribute__((address_space(3))) unsigned int*)&Bs[flat * 8], 16, 0, 0);
        }
        __syncthreads();

        const int kq = (lane >> 4) * 8;
        const int rl = lane & 15;
        s16x8 af[4], bfr[4];
#pragma unroll
        for (int mi = 0; mi < 4; mi++)
            af[mi] = *(const s16x8*)&As[(wm + mi * 16 + rl) * 32 + kq];
#pragma unroll
        for (int ni = 0; ni < 4; ni++)
            bfr[ni] = *(const s16x8*)&Bs[(wn + ni * 16 + rl) * 32 + kq];
#pragma unroll
        for (int mi = 0; mi < 4; mi++)
#pragma unroll
            for (int ni = 0; ni < 4; ni++)
                acc[mi][ni] = __builtin_amdgcn_mfma_f32_16x16x32_bf16(
                    af[mi], bfr[ni], acc[mi][ni], 0, 0, 0);
        __syncthreads();
    }

    const int cl = lane & 15;
    const int rq = (lane >> 4) * 4;
#pragma unroll
    for (int mi = 0; mi < 4; mi++)
#pragma unroll
        for (int ni = 0; ni < 4; ni++)
#pragma unroll
            for (int r = 0; r < 4; r++) {
                int row = bm + wm + mi * 16 + rq + r;
                int col = bn + wn + ni * 16 + cl;
                float v = acc[mi][ni][r];
                if (Cb) {
                    if (bias) v = fmaxf(v + bias[col], 0.f);
                    Cb[(size_t)row * N + col] = f2b(v);
                } else {
                    Cf[(size_t)row * N + col] = v;
                }
            }
}

// ---------------- CSR build ----------------
__global__ void count_kernel(const int* __restrict__ ei, int* __restrict__ counts) {
    int e = blockIdx.x * blockDim.x + threadIdx.x;
    if (e < NEDGES) atomicAdd(&counts[ei[NEDGES + e]], 1);
}

__global__ __launch_bounds__(1024) void scan_kernel(const int* __restrict__ counts,
                                                    int* __restrict__ row_ptr)
{
    __shared__ int sdata[1024];
    const int t = threadIdx.x;
    int vals[20];
    const int base = t * 20;
    int lsum = 0;
#pragma unroll
    for (int j = 0; j < 20; j++) {
        int idx = base + j;
        int v = (idx < NNODES) ? counts[idx] : 0;
        vals[j] = v; lsum += v;
    }
    sdata[t] = lsum;
    __syncthreads();
    for (int off = 1; off < 1024; off <<= 1) {
        int v = (t >= off) ? sdata[t - off] : 0;
        __syncthreads();
        sdata[t] += v;
        __syncthreads();
    }
    int run = sdata[t] - lsum;
#pragma unroll
    for (int j = 0; j < 20; j++) {
        int idx = base + j;
        if (idx < NNODES) row_ptr[idx] = run;
        run += vals[j];
    }
    if (t == 1023) row_ptr[NNODES] = sdata[1023];
}

__global__ void fill_kernel(const int* __restrict__ ei,
                            const int* __restrict__ row_ptr,
                            int* __restrict__ cursor,
                            int2* __restrict__ csr)   // {src, eid}
{
    int e = blockIdx.x * blockDim.x + threadIdx.x;
    if (e >= NEDGES) return;
    int dst = ei[NEDGES + e];
    int p = row_ptr[dst] + atomicAdd(&cursor[dst], 1);
    csr[p] = make_int2(ei[e], e);
}

__global__ void dinv_kernel(const int* __restrict__ row_ptr, float* __restrict__ dinv) {
    int i = blockIdx.x * blockDim.x + threadIdx.x;
    if (i < NNODES) {
        int deg = row_ptr[i + 1] - row_ptr[i] + 1;   // + self loop
        dinv[i] = rsqrtf((float)deg);
    }
}

// ---------------- packing ----------------
__global__ void pad_copy_kernel(const float* __restrict__ src,
                                unsigned short* __restrict__ dst,
                                int valid_rows, int cols, long total)
{
    long idx = (long)blockIdx.x * blockDim.x + threadIdx.x;
    if (idx >= total) return;
    int n = (int)(idx / cols);
    dst[idx] = (n < valid_rows) ? f2b(src[idx]) : (unsigned short)0;
}

// Interleaved P column layout (groups of 4 columns per channel pair):
//   cols [0,1024):   group cp: [f_dst[2cp], f_dst[2cp+1], s_dst[2cp], s_dst[2cp+1]]
//   cols [1024,2048): same for src projections
// -> per-edge gather reads ONE dwordx2.
__global__ void pack_cgw_kernel(const float* __restrict__ Wf,
                                const float* __restrict__ Ws,
                                unsigned short* __restrict__ out)
{
    int idx = blockIdx.x * blockDim.x + threadIdx.x;
    if (idx >= 2048 * 512) return;
    int j = idx >> 9;          // output column (wpack row) 0..2047
    int k = idx & 511;         // K index
    int half = (j >= 1024);    // 0 = dst block, 1 = src block
    int jj = j & 1023;
    int c  = (jj >> 2) * 2 + (jj & 1);   // channel
    int fs = (jj >> 1) & 1;              // 0 = f, 1 = s
    const float* W = fs ? Ws : Wf;
    float v = W[(size_t)(half ? 512 + k : k) * 512 + c];
    out[idx] = f2b(v);
}

__global__ void pack_t_kernel(const float* __restrict__ W,
                              unsigned short* __restrict__ WT,
                              int K, int Nout)
{
    long idx = (long)blockIdx.x * blockDim.x + threadIdx.x;
    if (idx >= (long)K * Nout) return;
    int j = (int)(idx / K);
    int k = (int)(idx % K);
    WT[idx] = f2b(W[(size_t)k * Nout + j]);
}

// W_e table in fp16 pairs for the gather's dot2 path:
// out dword idx = k*1024 + c2*4 + q, q: 0=f@c0 1=f@c1 2=s@c0 3=s@c1 (c0=2*c2)
// value = (W[1024+2k][c], W[1024+2k+1][c]) as 2 x fp16
__global__ void pack_we_kernel(const float* __restrict__ Wf,
                               const float* __restrict__ Ws,
                               unsigned int* __restrict__ out)
{
    int idx = blockIdx.x * blockDim.x + threadIdx.x;
    if (idx >= 8192) return;
    int q  = idx & 3;
    int c2 = (idx >> 2) & 255;
    int k  = idx >> 10;
    const float* W = (q >> 1) ? Ws : Wf;
    int c = c2 * 2 + (q & 1);
    float v0 = W[(size_t)(1024 + 2 * k) * 512 + c];
    float v1 = W[(size_t)(1024 + 2 * k + 1) * 512 + c];
    out[idx] = packh2(v0, v1);
}

// edge attrs as fp16 pairs in CSR order: eapk[i][j] = (ea[eid][2j], ea[eid][2j+1])
__global__ void pack_ea_kernel(const int2* __restrict__ csr,
                               const float* __restrict__ ea,
                               unsigned int* __restrict__ out)
{
    int idx = blockIdx.x * blockDim.x + threadIdx.x;
    if (idx >= NEDGES * 8) return;
    int i = idx >> 3;
    int j = idx & 7;
    int eid = csr[i].y;
    out[idx] = packh2(ea[(size_t)eid * 16 + 2 * j], ea[(size_t)eid * 16 + 2 * j + 1]);
}

// ---------------- CGConv gather (fp16 dot2 path) ----------------
// Per thread: channel pair (c0, c0+1). Weight table wE (32 KB, hot in L1) loaded
// as 8 x dwordx4; compiler free to keep (32 VGPR) or reload per pair — both cheap.
// R2 lesson: do NOT pin weights with asm constraints (compiler spilled to scratch).
// Edge attrs pre-packed fp16 in CSR order -> streaming uniform loads, no csr[i].y.
#define CG_NPB 4
__global__ __launch_bounds__(256, 1) void cg_gather_kernel(
    const unsigned short* __restrict__ P,
    const int* __restrict__ row_ptr,
    const int2* __restrict__ csr,
    const u32x4* __restrict__ wE,     // [8][256] fp16-pair weight table
    const u32x4* __restrict__ eapk,   // [NEDGES][2] fp16-pair attrs, CSR order
    const float* __restrict__ bfv,
    const float* __restrict__ bsv,
    const float* __restrict__ g,
    const float* __restrict__ be,
    const float* __restrict__ xresf,          // fp32 [NNODES,512] or null
    const unsigned short* __restrict__ xresb, // bf16 [NPAD,512] or null
    unsigned short* __restrict__ hout)
{
    const int tid = threadIdx.x;
    const int c0  = tid * 2;
    const int nbase = blockIdx.x * CG_NPB;

    u32x4 w[8];
#pragma unroll
    for (int k = 0; k < 8; k++) w[k] = wE[k * 256 + tid];

    const f32x2 bfx = *(const f32x2*)&bfv[c0];
    const f32x2 bsx = *(const f32x2*)&bsv[c0];
    const f32x2 gv  = *(const f32x2*)&g[c0];
    const f32x2 bev = *(const f32x2*)&be[c0];
    const float rs = rsqrtf(1.f + 1e-5f);

    for (int n = nbase; n < nbase + CG_NPB; n++) {
        if (n >= NNODES) {
            *(unsigned int*)&hout[(size_t)n * 512 + c0] = 0;
            continue;
        }
        const unsigned short* Pd = P + (size_t)n * 2048;
        const uint2 qb = *(const uint2*)(Pd + c0 * 2);
        const f32x2 baseF = unpack2(qb.x) + bfx;
        const f32x2 baseS = unpack2(qb.y) + bsx;

        f32x2 acc = {0.f, 0.f};
        const int i0 = row_ptr[n], i1 = row_ptr[n + 1];

        auto do_edge = [&](int i) {
            const int sx = __builtin_amdgcn_readfirstlane(csr[i].x);
            u32x4 a0 = eapk[(size_t)i * 2];
            u32x4 a1 = eapk[(size_t)i * 2 + 1];
            uint2 q = *(const uint2*)(P + (size_t)sx * 2048 + 1024 + c0 * 2);
            float f0 = baseF.x, f1 = baseF.y, s0 = baseS.x, s1 = baseS.y;
#pragma unroll
            for (int k = 0; k < 4; k++) {
                f0 = dot2h(a0[k], w[k][0], f0);
                f1 = dot2h(a0[k], w[k][1], f1);
                s0 = dot2h(a0[k], w[k][2], s0);
                s1 = dot2h(a0[k], w[k][3], s1);
            }
#pragma unroll
            for (int k = 0; k < 4; k++) {
                f0 = dot2h(a1[k], w[4 + k][0], f0);
                f1 = dot2h(a1[k], w[4 + k][1], f1);
                s0 = dot2h(a1[k], w[4 + k][2], s0);
                s1 = dot2h(a1[k], w[4 + k][3], s1);
            }
            f32x2 pf = unpack2(q.x);
            f32x2 ps = unpack2(q.y);
            f0 += pf.x; f1 += pf.y; s0 += ps.x; s1 += ps.y;
            float sp0 = __logf(1.f + __expf(s0));
            float sp1 = __logf(1.f + __expf(s1));
            float sg0 = __builtin_amdgcn_rcpf(1.f + __expf(-f0));
            float sg1 = __builtin_amdgcn_rcpf(1.f + __expf(-f1));
            acc.x = fmaf(sp0, sg0, acc.x);
            acc.y = fmaf(sp1, sg1, acc.y);
        };

        int i = i0;
        for (; i + 1 < i1; i += 2) {   // pairs: one weight fetch serves 2 edges
            do_edge(i);
            do_edge(i + 1);
        }
        if (i < i1) do_edge(i);

        // fused BN(eval) + residual + ReLU
        f32x2 res;
        if (xresf) {
            res = *(const f32x2*)&xresf[(size_t)n * 512 + c0];
        } else {
            res = unpack2(*(const unsigned int*)&xresb[(size_t)n * 512 + c0]);
        }
        float v0 = fmaxf(acc.x * (gv.x * rs) + bev.x + res.x, 0.f);
        float v1 = fmaxf(acc.y * (gv.y * rs) + bev.y + res.y, 0.f);
        unsigned int packed = (unsigned int)f2b(v0) | ((unsigned int)f2b(v1) << 16);
        *(unsigned int*)&hout[(size_t)n * 512 + c0] = packed;
    }
}

// ---------------- GCN gather (2 nodes/block, 2 ch/thread, scalarized src) ----------------
__global__ __launch_bounds__(256) void gcn_gather_kernel(
    const unsigned short* __restrict__ pre,   // bf16 [NPAD,256]
    const int* __restrict__ row_ptr,
    const int2* __restrict__ csr,
    const float* __restrict__ dinv,
    const float* __restrict__ b,
    unsigned short* __restrict__ hout,  // bf16 [NPAD,256]
    float* __restrict__ doutf)          // fp32 [NNODES,256] or null
{
    const int tid = threadIdx.x;
    const int n = blockIdx.x * 2 + (tid >> 7);   // waves 0-1 -> node A, 2-3 -> node B
    const int c = (tid & 127) * 2;
    if (n >= NNODES) {
        if (n < NPAD) *(unsigned int*)&hout[(size_t)n * 256 + c] = 0;
        return;
    }
    const float din = dinv[n];
    f32x2 acc = {0.f, 0.f};
    const int i0 = row_ptr[n], i1 = row_ptr[n + 1];
    if (i0 < i1) {
        int sx = __builtin_amdgcn_readfirstlane(csr[i0].x);
        float dv = dinv[sx];
        unsigned int pv = *(const unsigned int*)&pre[(size_t)sx * 256 + c];
        for (int i = i0; i < i1; i++) {
            float cdv = dv; unsigned int cpv = pv;
            if (i + 1 < i1) {
                int sx2 = __builtin_amdgcn_readfirstlane(csr[i + 1].x);
                dv = dinv[sx2];
                pv = *(const unsigned int*)&pre[(size_t)sx2 * 256 + c];
            }
            f32x2 p = unpack2(cpv);
            acc.x = fmaf(cdv, p.x, acc.x);
            acc.y = fmaf(cdv, p.y, acc.y);
        }
    }
    f32x2 self = unpack2(*(const unsigned int*)&pre[(size_t)n * 256 + c]);
    const f32x2 bv = *(const f32x2*)&b[c];
    float v0 = fmaxf(fmaf(acc.x, din, din * din * self.x) + bv.x, 0.f);
    float v1 = fmaxf(fmaf(acc.y, din, din * din * self.y) + bv.y, 0.f);
    *(unsigned int*)&hout[(size_t)n * 256 + c] =
        (unsigned int)f2b(v0) | ((unsigned int)f2b(v1) << 16);
    if (doutf) {
        f32x2 vv = {v0, v1};
        *(f32x2*)&doutf[(size_t)n * 256 + c] = vv;
    }
}

// ---------------- MLP ----------------
__global__ void build_zc_kernel(const unsigned short* __restrict__ h4,
                                const float* __restrict__ goal,
                                unsigned short* __restrict__ zc)
{
    long idx = (long)blockIdx.x * blockDim.x + threadIdx.x;
    if (idx >= (long)NPAD * 768) return;
    int n = (int)(idx / 768);
    int c = (int)(idx % 768);
    unsigned short v = 0;
    if (n < NNODES)
        v = (c < 256) ? h4[(size_t)n * 256 + c]
                      : f2b(goal[(size_t)n * 512 + (c - 256)]);
    zc[idx] = v;
}

__global__ __launch_bounds__(256) void final_dot_kernel(
    const unsigned short* __restrict__ t,
    const float* __restrict__ Wd2,
    const float* __restrict__ bd2,
    float* __restrict__ pred)
{
    const int lane = threadIdx.x & 63;
    const int wid  = threadIdx.x >> 6;
    float w[8];
#pragma unroll
    for (int i = 0; i < 8; i++) w[i] = Wd2[lane * 8 + i];
    const float bd = bd2[0];
    for (int n = blockIdx.x * 4 + wid; n < NNODES; n += gridDim.x * 4) {
        const unsigned short* tp = t + (size_t)n * 512 + lane * 8;
        float s = 0.f;
#pragma unroll
        for (int i = 0; i < 8; i++) s = fmaf(b2f(tp[i]), w[i], s);
#pragma unroll
        for (int off = 32; off; off >>= 1) s += __shfl_xor(s, off, 64);
        if (lane == 0) pred[n] = s + bd;
    }
}

// ---------------- launcher ----------------
extern "C" void kernel_launch(void* const* d_in, const int* in_sizes, int n_in,
                              void* d_out, int out_size, void* d_ws, size_t ws_size,
                              hipStream_t stream)
{
    (void)in_sizes; (void)n_in; (void)out_size; (void)ws_size;
    const float* x    = (const float*)d_in[0];
    const int*   ei   = (const int*)d_in[1];
    const float* ea   = (const float*)d_in[2];
    const float* goal = (const float*)d_in[3];
    const float* Wf1  = (const float*)d_in[4];
    const float* bf1  = (const float*)d_in[5];
    const float* Ws1  = (const float*)d_in[6];
    const float* bs1  = (const float*)d_in[7];
    const float* g1   = (const float*)d_in[8];
    const float* be1  = (const float*)d_in[9];
    const float* Wf2  = (const float*)d_in[10];
    const float* bf2  = (const float*)d_in[11];
    const float* Ws2  = (const float*)d_in[12];
    const float* bs2  = (const float*)d_in[13];
    const float* g2   = (const float*)d_in[14];
    const float* be2  = (const float*)d_in[15];
    const float* W3   = (const float*)d_in[16];
    const float* b3   = (const float*)d_in[17];
    const float* W4   = (const float*)d_in[18];
    const float* b4   = (const float*)d_in[19];
    const float* Wd1  = (const float*)d_in[20];
    const float* bd1  = (const float*)d_in[21];
    const float* Wd2  = (const float*)d_in[22];
    const float* bd2  = (const float*)d_in[23];
    float* outp = (float*)d_out;   // fp32: [0..N) pred, [N..N+N*256) h

    char* ws = (char*)d_ws;
    size_t off = 0;
    auto alloc = [&](size_t bytes) -> char* {
        char* p = ws + off;
        off += (bytes + 255) & ~(size_t)255;
        return p;
    };
    unsigned short* P     = (unsigned short*)alloc((size_t)NPAD * 2048 * 2); // later zc + tb
    unsigned short* bufA  = (unsigned short*)alloc((size_t)NPAD * 512 * 2);  // xpad / h2 / h4
    unsigned short* bufB  = (unsigned short*)alloc((size_t)NPAD * 512 * 2);  // h1 / pre_b
    unsigned short* bufC  = (unsigned short*)alloc((size_t)NPAD * 512 * 2);  // h3
    unsigned short* wpack = (unsigned short*)alloc((size_t)2048 * 512 * 2);
    int*            counts  = (int*)alloc((size_t)NNODES * 4);
    int*            row_ptr = (int*)alloc((size_t)(NNODES + 1) * 4);
    int2*           csr     = (int2*)alloc((size_t)NEDGES * 8);
    float*          dinv    = (float*)alloc((size_t)NNODES * 4);
    unsigned int*   wEbuf   = (unsigned int*)alloc((size_t)8192 * 4);
    unsigned int*   eapk    = (unsigned int*)alloc((size_t)NEDGES * 8 * 4);

    unsigned short* xpad  = bufA;
    unsigned short* h1    = bufB;
    unsigned short* h2    = bufA;
    unsigned short* pre_b = bufB;
    unsigned short* h3    = bufC;
    unsigned short* h4    = bufA;
    unsigned short* zc    = P;
    unsigned short* tb    = P + (size_t)NPAD * 1024;

    const int B = 256;

    // ---- CSR build (by destination) + dinv ----
    hipMemsetAsync(counts, 0, (size_t)NNODES * 4, stream);
    count_kernel<<<(NEDGES + B - 1) / B, B, 0, stream>>>(ei, counts);
    scan_kernel<<<1, 1024, 0, stream>>>(counts, row_ptr);
    hipMemsetAsync(counts, 0, (size_t)NNODES * 4, stream);
    fill_kernel<<<(NEDGES + B - 1) / B, B, 0, stream>>>(ei, row_ptr, counts, csr);
    dinv_kernel<<<(NNODES + B - 1) / B, B, 0, stream>>>(row_ptr, dinv);
    pack_ea_kernel<<<(NEDGES * 8 + B - 1) / B, B, 0, stream>>>(csr, ea, eapk);

    {
        long tot = (long)NPAD * 512;
        pad_copy_kernel<<<(unsigned)((tot + B - 1) / B), B, 0, stream>>>(x, xpad, NNODES, 512, tot);
    }

    dim3 gBig(NPAD / 128, 2048 / 128);

    // ---- CGConv layer 1 ----
    pack_cgw_kernel<<<(2048 * 512 + B - 1) / B, B, 0, stream>>>(Wf1, Ws1, wpack);
    pack_we_kernel<<<(8192 + B - 1) / B, B, 0, stream>>>(Wf1, Ws1, wEbuf);
    gemm_bt_kernel<<<gBig, B, 0, stream>>>(xpad, wpack, nullptr, P, NPAD, 2048, 512, nullptr);
    cg_gather_kernel<<<NPAD / CG_NPB, B, 0, stream>>>(P, row_ptr, csr,
                                                      (const u32x4*)wEbuf, (const u32x4*)eapk,
                                                      bf1, bs1, g1, be1,
                                                      x, nullptr, h1);

    // ---- CGConv layer 2 ----
    pack_cgw_kernel<<<(2048 * 512 + B - 1) / B, B, 0, stream>>>(Wf2, Ws2, wpack);
    gemm_bt_kernel<<<gBig, B, 0, stream>>>(h1, wpack, nullptr, P, NPAD, 2048, 512, nullptr);
    pack_we_kernel<<<(8192 + B - 1) / B, B, 0, stream>>>(Wf2, Ws2, wEbuf);
    cg_gather_kernel<<<NPAD / CG_NPB, B, 0, stream>>>(P, row_ptr, csr,
                                                      (const u32x4*)wEbuf, (const u32x4*)eapk,
                                                      bf2, bs2, g2, be2,
                                                      nullptr, h1, h2);

    // ---- GCN layer 3 ----
    pack_t_kernel<<<(256 * 512 + B - 1) / B, B, 0, stream>>>(W3, wpack, 512, 256);
    gemm_bt_kernel<<<dim3(NPAD / 128, 2), B, 0, stream>>>(h2, wpack, nullptr, pre_b, NPAD, 256, 512, nullptr);
    gcn_gather_kernel<<<NPAD / 2, B, 0, stream>>>(pre_b, row_ptr, csr, dinv, b3, h3, (float*)nullptr);

    // ---- GCN layer 4 ----
    pack_t_kernel<<<(256 * 256 + B - 1) / B, B, 0, stream>>>(W4, wpack, 256, 256);
    gemm_bt_kernel<<<dim3(NPAD / 128, 2), B, 0, stream>>>(h3, wpack, nullptr, pre_b, NPAD, 256, 256, nullptr);
    gcn_gather_kernel<<<NPAD / 2, B, 0, stream>>>(pre_b, row_ptr, csr, dinv, b4, h4, outp + NNODES);

    // ---- distance MLP (bias+ReLU fused into GEMM epilogue) ----
    build_zc_kernel<<<(unsigned)(((long)NPAD * 768 + B - 1) / B), B, 0, stream>>>(h4, goal, zc);
    pack_t_kernel<<<(512 * 768 + B - 1) / B, B, 0, stream>>>(Wd1, wpack, 768, 512);
    gemm_bt_kernel<<<dim3(NPAD / 128, 4), B, 0, stream>>>(zc, wpack, nullptr, tb, NPAD, 512, 768, bd1);
    final_dot_kernel<<<512, B, 0, stream>>>(tb, Wd2, bd2, outp);
}

// Round 4
// 793.952 us; speedup vs baseline: 1.1589x; 1.0346x over previous
//
#include <hip/hip_runtime.h>
#include <stdint.h>

#define NNODES 20000
#define NEDGES 160000
#define NPAD   20096   // 157 * 128

typedef float f32x4 __attribute__((ext_vector_type(4)));
typedef float f32x2 __attribute__((ext_vector_type(2)));
typedef short s16x8 __attribute__((ext_vector_type(8)));
typedef unsigned int u32x4 __attribute__((ext_vector_type(4)));
typedef _Float16 h16x2 __attribute__((ext_vector_type(2)));

__device__ __forceinline__ float b2f(unsigned short b) {
    unsigned int u = ((unsigned int)b) << 16;
    return __builtin_bit_cast(float, u);
}
__device__ __forceinline__ unsigned short f2b(float f) {
    unsigned int u = __builtin_bit_cast(unsigned int, f);
    unsigned int r = (u + 0x7FFFu + ((u >> 16) & 1u)) >> 16;
    return (unsigned short)r;
}
// unpack 2 bf16 (packed in a dword) -> float2
__device__ __forceinline__ f32x2 unpack2(unsigned int u) {
    f32x2 r;
    r.x = __builtin_bit_cast(float, u << 16);
    r.y = __builtin_bit_cast(float, u & 0xFFFF0000u);
    return r;
}
// pack two fp32 -> fp16 pair in a dword
__device__ __forceinline__ unsigned int packh2(float a, float b) {
    h16x2 h = { (_Float16)a, (_Float16)b };
    return __builtin_bit_cast(unsigned int, h);
}
// fp16-pair dot with fp32 accumulate: one v_dot2_f32_f16
__device__ __forceinline__ float dot2h(unsigned int a, unsigned int b, float c) {
#if __has_builtin(__builtin_amdgcn_fdot2)
    return __builtin_amdgcn_fdot2(__builtin_bit_cast(h16x2, a),
                                  __builtin_bit_cast(h16x2, b), c, false);
#else
    float d;
    asm("v_dot2_f32_f16 %0, %1, %2, %3" : "=v"(d) : "v"(a), "v"(b), "v"(c));
    return d;
#endif
}

// ---- GEMM: C[M,N] = A[M,K](bf16) @ BT[N,K]^T(bf16); C fp32 or bf16 ----
__global__ __launch_bounds__(256) void gemm_bt_kernel(
    const unsigned short* __restrict__ A,
    const unsigned short* __restrict__ BT,
    float* __restrict__ Cf,
    unsigned short* __restrict__ Cb,
    int M, int N, int K,
    const float* __restrict__ bias)
{
    __shared__ unsigned short As[128 * 32];
    __shared__ unsigned short Bs[128 * 32];
    const int tid  = threadIdx.x;
    const int wid  = tid >> 6;
    const int lane = tid & 63;
    const int bm = blockIdx.x * 128;
    const int bn = blockIdx.y * 128;
    const int wm = (wid & 1) * 64;
    const int wn = (wid >> 1) * 64;

    f32x4 acc[4][4];
#pragma unroll
    for (int i = 0; i < 4; i++)
#pragma unroll
        for (int j = 0; j < 4; j++) acc[i][j] = {0.f, 0.f, 0.f, 0.f};

    for (int k0 = 0; k0 < K; k0 += 32) {
#pragma unroll
        for (int r = 0; r < 2; r++) {
            int flat = r * 256 + tid;
            int row  = flat >> 2;
            int part = flat & 3;
            const unsigned short* ga = A  + (size_t)(bm + row) * K + k0 + part * 8;
            const unsigned short* gb = BT + (size_t)(bn + row) * K + k0 + part * 8;
            __builtin_amdgcn_global_load_lds(
                (const __attribute__((address_space(1))) unsigned int*)ga,
                (__attribute__((address_space(3))) unsigned int*)&As[flat * 8], 16, 0, 0);
            __builtin_amdgcn_global_load_lds(
                (const __attribute__((address_space(1))) unsigned int*)gb,
                (__attribute__((address_space(3))) unsigned int*)&Bs[flat * 8], 16, 0, 0);
        }
        __syncthreads();

        const int kq = (lane >> 4) * 8;
        const int rl = lane & 15;
        s16x8 af[4], bfr[4];
#pragma unroll
        for (int mi = 0; mi < 4; mi++)
            af[mi] = *(const s16x8*)&As[(wm + mi * 16 + rl) * 32 + kq];
#pragma unroll
        for (int ni = 0; ni < 4; ni++)
            bfr[ni] = *(const s16x8*)&Bs[(wn + ni * 16 + rl) * 32 + kq];
#pragma unroll
        for (int mi = 0; mi < 4; mi++)
#pragma unroll
            for (int ni = 0; ni < 4; ni++)
                acc[mi][ni] = __builtin_amdgcn_mfma_f32_16x16x32_bf16(
                    af[mi], bfr[ni], acc[mi][ni], 0, 0, 0);
        __syncthreads();
    }

    const int cl = lane & 15;
    const int rq = (lane >> 4) * 4;
#pragma unroll
    for (int mi = 0; mi < 4; mi++)
#pragma unroll
        for (int ni = 0; ni < 4; ni++)
#pragma unroll
            for (int r = 0; r < 4; r++) {
                int row = bm + wm + mi * 16 + rq + r;
                int col = bn + wn + ni * 16 + cl;
                float v = acc[mi][ni][r];
                if (Cb) {
                    if (bias) v = fmaxf(v + bias[col], 0.f);
                    Cb[(size_t)row * N + col] = f2b(v);
                } else {
                    Cf[(size_t)row * N + col] = v;
                }
            }
}

// ---------------- CSR build ----------------
__global__ void count_kernel(const int* __restrict__ ei, int* __restrict__ counts) {
    int e = blockIdx.x * blockDim.x + threadIdx.x;
    if (e < NEDGES) atomicAdd(&counts[ei[NEDGES + e]], 1);
}

__global__ __launch_bounds__(1024) void scan_kernel(const int* __restrict__ counts,
                                                    int* __restrict__ row_ptr)
{
    __shared__ int sdata[1024];
    const int t = threadIdx.x;
    int vals[20];
    const int base = t * 20;
    int lsum = 0;
#pragma unroll
    for (int j = 0; j < 20; j++) {
        int idx = base + j;
        int v = (idx < NNODES) ? counts[idx] : 0;
        vals[j] = v; lsum += v;
    }
    sdata[t] = lsum;
    __syncthreads();
    for (int off = 1; off < 1024; off <<= 1) {
        int v = (t >= off) ? sdata[t - off] : 0;
        __syncthreads();
        sdata[t] += v;
        __syncthreads();
    }
    int run = sdata[t] - lsum;
#pragma unroll
    for (int j = 0; j < 20; j++) {
        int idx = base + j;
        if (idx < NNODES) row_ptr[idx] = run;
        run += vals[j];
    }
    if (t == 1023) row_ptr[NNODES] = sdata[1023];
}

__global__ void fill_kernel(const int* __restrict__ ei,
                            const int* __restrict__ row_ptr,
                            int* __restrict__ cursor,
                            int* __restrict__ csr_src,
                            int* __restrict__ csr_eid)
{
    int e = blockIdx.x * blockDim.x + threadIdx.x;
    if (e >= NEDGES) return;
    int dst = ei[NEDGES + e];
    int p = row_ptr[dst] + atomicAdd(&cursor[dst], 1);
    csr_src[p] = ei[e];
    csr_eid[p] = e;
}

__global__ void dinv_kernel(const int* __restrict__ row_ptr, float* __restrict__ dinv) {
    int i = blockIdx.x * blockDim.x + threadIdx.x;
    if (i < NNODES) {
        int deg = row_ptr[i + 1] - row_ptr[i] + 1;   // + self loop
        dinv[i] = rsqrtf((float)deg);
    }
}

// ---------------- packing ----------------
__global__ void pad_copy_kernel(const float* __restrict__ src,
                                unsigned short* __restrict__ dst,
                                int valid_rows, int cols, long total)
{
    long idx = (long)blockIdx.x * blockDim.x + threadIdx.x;
    if (idx >= total) return;
    int n = (int)(idx / cols);
    dst[idx] = (n < valid_rows) ? f2b(src[idx]) : (unsigned short)0;
}

// Interleaved P column layout (groups of 4 columns per channel pair):
//   cols [0,1024):   group cp: [f_dst[2cp], f_dst[2cp+1], s_dst[2cp], s_dst[2cp+1]]
//   cols [1024,2048): same for src projections
// -> per-edge gather reads ONE dwordx2.
__global__ void pack_cgw_kernel(const float* __restrict__ Wf,
                                const float* __restrict__ Ws,
                                unsigned short* __restrict__ out)
{
    int idx = blockIdx.x * blockDim.x + threadIdx.x;
    if (idx >= 2048 * 512) return;
    int j = idx >> 9;          // output column (wpack row) 0..2047
    int k = idx & 511;         // K index
    int half = (j >= 1024);    // 0 = dst block, 1 = src block
    int jj = j & 1023;
    int c  = (jj >> 2) * 2 + (jj & 1);   // channel
    int fs = (jj >> 1) & 1;              // 0 = f, 1 = s
    const float* W = fs ? Ws : Wf;
    float v = W[(size_t)(half ? 512 + k : k) * 512 + c];
    out[idx] = f2b(v);
}

__global__ void pack_t_kernel(const float* __restrict__ W,
                              unsigned short* __restrict__ WT,
                              int K, int Nout)
{
    long idx = (long)blockIdx.x * blockDim.x + threadIdx.x;
    if (idx >= (long)K * Nout) return;
    int j = (int)(idx / K);
    int k = (int)(idx % K);
    WT[idx] = f2b(W[(size_t)k * Nout + j]);
}

// W_e table in fp16 pairs for the gather's dot2 path:
// out dword idx = k*1024 + c2*4 + q, q: 0=f@c0 1=f@c1 2=s@c0 3=s@c1 (c0=2*c2)
// value = (W[1024+2k][c], W[1024+2k+1][c]) as 2 x fp16
__global__ void pack_we_kernel(const float* __restrict__ Wf,
                               const float* __restrict__ Ws,
                               unsigned int* __restrict__ out)
{
    int idx = blockIdx.x * blockDim.x + threadIdx.x;
    if (idx >= 8192) return;
    int q  = idx & 3;
    int c2 = (idx >> 2) & 255;
    int k  = idx >> 10;
    const float* W = (q >> 1) ? Ws : Wf;
    int c = c2 * 2 + (q & 1);
    float v0 = W[(size_t)(1024 + 2 * k) * 512 + c];
    float v1 = W[(size_t)(1024 + 2 * k + 1) * 512 + c];
    out[idx] = packh2(v0, v1);
}

// edge attrs as fp16 pairs in CSR order: eapk[i][j] = (ea[eid][2j], ea[eid][2j+1])
__global__ void pack_ea_kernel(const int* __restrict__ csr_eid,
                               const float* __restrict__ ea,
                               unsigned int* __restrict__ out)
{
    int idx = blockIdx.x * blockDim.x + threadIdx.x;
    if (idx >= NEDGES * 8) return;
    int i = idx >> 3;
    int j = idx & 7;
    int eid = csr_eid[i];
    out[idx] = packh2(ea[(size_t)eid * 16 + 2 * j], ea[(size_t)eid * 16 + 2 * j + 1]);
}

// ---------------- CGConv gather (fp16 dot2 + scalar indices + depth-2 pipeline) ----
// All edge-loop indices are forced into SGPRs (readfirstlane on row_ptr), so
// csr_src / eapk loads are uniform (SMEM path) and the only per-lane VMEM in the
// loop is the 8B P-src gather. Named A/B register sets (no runtime indexing).
#define CG_NPB 2

#define CG_LOADE(q_, a0_, a1_, idx) do {                                       \
    int sx_ = __builtin_amdgcn_readfirstlane(csr_src[idx]);                    \
    q_  = *(const uint2*)(P + (size_t)sx_ * 2048 + 1024 + c0 * 2);             \
    a0_ = eapk[(size_t)(idx) * 2];                                             \
    a1_ = eapk[(size_t)(idx) * 2 + 1];                                         \
} while (0)

#define CG_COMP(q_, a0_, a1_) do {                                             \
    float f0 = baseF.x, f1 = baseF.y, s0 = baseS.x, s1 = baseS.y;              \
    _Pragma("unroll")                                                          \
    for (int k = 0; k < 4; k++) {                                              \
        f0 = dot2h(a0_[k], w[k][0], f0);                                       \
        f1 = dot2h(a0_[k], w[k][1], f1);                                       \
        s0 = dot2h(a0_[k], w[k][2], s0);                                       \
        s1 = dot2h(a0_[k], w[k][3], s1);                                       \
    }                                                                          \
    _Pragma("unroll")                                                          \
    for (int k = 0; k < 4; k++) {                                              \
        f0 = dot2h(a1_[k], w[4 + k][0], f0);                                   \
        f1 = dot2h(a1_[k], w[4 + k][1], f1);                                   \
        s0 = dot2h(a1_[k], w[4 + k][2], s0);                                   \
        s1 = dot2h(a1_[k], w[4 + k][3], s1);                                   \
    }                                                                          \
    f32x2 pf = unpack2(q_.x);                                                  \
    f32x2 ps = unpack2(q_.y);                                                  \
    f0 += pf.x; f1 += pf.y; s0 += ps.x; s1 += ps.y;                            \
    float sp0 = __logf(1.f + __expf(s0));                                      \
    float sp1 = __logf(1.f + __expf(s1));                                      \
    float sg0 = __builtin_amdgcn_rcpf(1.f + __expf(-f0));                      \
    float sg1 = __builtin_amdgcn_rcpf(1.f + __expf(-f1));                      \
    acc.x = fmaf(sp0, sg0, acc.x);                                             \
    acc.y = fmaf(sp1, sg1, acc.y);                                             \
} while (0)

__global__ __launch_bounds__(256, 1) void cg_gather_kernel(
    const unsigned short* __restrict__ P,
    const int* __restrict__ row_ptr,
    const int* __restrict__ csr_src,
    const u32x4* __restrict__ wE,     // [8][256] fp16-pair weight table
    const u32x4* __restrict__ eapk,   // [NEDGES][2] fp16-pair attrs, CSR order
    const float* __restrict__ bfv,
    const float* __restrict__ bsv,
    const float* __restrict__ g,
    const float* __restrict__ be,
    const float* __restrict__ xresf,          // fp32 [NNODES,512] or null
    const unsigned short* __restrict__ xresb, // bf16 [NPAD,512] or null
    unsigned short* __restrict__ hout)
{
    const int tid = threadIdx.x;
    const int c0  = tid * 2;
    const int nbase = blockIdx.x * CG_NPB;

    u32x4 w[8];
#pragma unroll
    for (int k = 0; k < 8; k++) w[k] = wE[k * 256 + tid];

    const f32x2 bfx = *(const f32x2*)&bfv[c0];
    const f32x2 bsx = *(const f32x2*)&bsv[c0];
    const f32x2 gv  = *(const f32x2*)&g[c0];
    const f32x2 bev = *(const f32x2*)&be[c0];
    const float rs = rsqrtf(1.f + 1e-5f);

    for (int n = nbase; n < nbase + CG_NPB; n++) {
        if (n >= NNODES) {
            *(unsigned int*)&hout[(size_t)n * 512 + c0] = 0;
            continue;
        }
        const unsigned short* Pd = P + (size_t)n * 2048;
        const uint2 qb = *(const uint2*)(Pd + c0 * 2);
        const f32x2 baseF = unpack2(qb.x) + bfx;
        const f32x2 baseS = unpack2(qb.y) + bsx;

        f32x2 acc = {0.f, 0.f};
        const int i0 = __builtin_amdgcn_readfirstlane(row_ptr[n]);
        const int i1 = __builtin_amdgcn_readfirstlane(row_ptr[n + 1]);

        if (i0 < i1) {
            uint2 qA = {}, qB = {};
            u32x4 aA0 = {}, aA1 = {}, aB0 = {}, aB1 = {};
            CG_LOADE(qA, aA0, aA1, i0);
            if (i0 + 1 < i1) CG_LOADE(qB, aB0, aB1, i0 + 1);
            int i = i0;
            while (i < i1) {
                CG_COMP(qA, aA0, aA1);
                if (i + 2 < i1) CG_LOADE(qA, aA0, aA1, i + 2);
                if (++i >= i1) break;
                CG_COMP(qB, aB0, aB1);
                if (i + 2 < i1) CG_LOADE(qB, aB0, aB1, i + 2);
                ++i;
            }
        }

        // fused BN(eval) + residual + ReLU
        f32x2 res;
        if (xresf) {
            res = *(const f32x2*)&xresf[(size_t)n * 512 + c0];
        } else {
            res = unpack2(*(const unsigned int*)&xresb[(size_t)n * 512 + c0]);
        }
        float v0 = fmaxf(acc.x * (gv.x * rs) + bev.x + res.x, 0.f);
        float v1 = fmaxf(acc.y * (gv.y * rs) + bev.y + res.y, 0.f);
        unsigned int packed = (unsigned int)f2b(v0) | ((unsigned int)f2b(v1) << 16);
        *(unsigned int*)&hout[(size_t)n * 512 + c0] = packed;
    }
}

// ---------------- GCN gather (scalar indices + depth-2 pipeline) ----------------
__global__ __launch_bounds__(256) void gcn_gather_kernel(
    const unsigned short* __restrict__ pre,   // bf16 [NPAD,256]
    const int* __restrict__ row_ptr,
    const int* __restrict__ csr_src,
    const float* __restrict__ dinv,
    const float* __restrict__ b,
    unsigned short* __restrict__ hout,  // bf16 [NPAD,256]
    float* __restrict__ doutf)          // fp32 [NNODES,256] or null
{
    const int tid = threadIdx.x;
    const int n = blockIdx.x * 2 + (tid >> 7);   // waves 0-1 -> node A, 2-3 -> node B
    const int c = (tid & 127) * 2;
    if (n >= NNODES) {
        if (n < NPAD) *(unsigned int*)&hout[(size_t)n * 256 + c] = 0;
        return;
    }
    const float din = dinv[n];
    f32x2 acc = {0.f, 0.f};
    const int i0 = __builtin_amdgcn_readfirstlane(row_ptr[n]);
    const int i1 = __builtin_amdgcn_readfirstlane(row_ptr[n + 1]);
    if (i0 < i1) {
        float dvA = 0.f, dvB = 0.f;
        unsigned int pvA = 0, pvB = 0;
        {
            int sx = __builtin_amdgcn_readfirstlane(csr_src[i0]);
            dvA = dinv[sx];
            pvA = *(const unsigned int*)&pre[(size_t)sx * 256 + c];
        }
        if (i0 + 1 < i1) {
            int sx = __builtin_amdgcn_readfirstlane(csr_src[i0 + 1]);
            dvB = dinv[sx];
            pvB = *(const unsigned int*)&pre[(size_t)sx * 256 + c];
        }
        int i = i0;
        while (i < i1) {
            {
                f32x2 p = unpack2(pvA);
                acc.x = fmaf(dvA, p.x, acc.x);
                acc.y = fmaf(dvA, p.y, acc.y);
            }
            if (i + 2 < i1) {
                int sx = __builtin_amdgcn_readfirstlane(csr_src[i + 2]);
                dvA = dinv[sx];
                pvA = *(const unsigned int*)&pre[(size_t)sx * 256 + c];
            }
            if (++i >= i1) break;
            {
                f32x2 p = unpack2(pvB);
                acc.x = fmaf(dvB, p.x, acc.x);
                acc.y = fmaf(dvB, p.y, acc.y);
            }
            if (i + 2 < i1) {
                int sx = __builtin_amdgcn_readfirstlane(csr_src[i + 2]);
                dvB = dinv[sx];
                pvB = *(const unsigned int*)&pre[(size_t)sx * 256 + c];
            }
            ++i;
        }
    }
    f32x2 self = unpack2(*(const unsigned int*)&pre[(size_t)n * 256 + c]);
    const f32x2 bv = *(const f32x2*)&b[c];
    float v0 = fmaxf(fmaf(acc.x, din, din * din * self.x) + bv.x, 0.f);
    float v1 = fmaxf(fmaf(acc.y, din, din * din * self.y) + bv.y, 0.f);
    *(unsigned int*)&hout[(size_t)n * 256 + c] =
        (unsigned int)f2b(v0) | ((unsigned int)f2b(v1) << 16);
    if (doutf) {
        f32x2 vv = {v0, v1};
        *(f32x2*)&doutf[(size_t)n * 256 + c] = vv;
    }
}

// ---------------- MLP ----------------
__global__ void build_zc_kernel(const unsigned short* __restrict__ h4,
                                const float* __restrict__ goal,
                                unsigned short* __restrict__ zc)
{
    long idx = (long)blockIdx.x * blockDim.x + threadIdx.x;
    if (idx >= (long)NPAD * 768) return;
    int n = (int)(idx / 768);
    int c = (int)(idx % 768);
    unsigned short v = 0;
    if (n < NNODES)
        v = (c < 256) ? h4[(size_t)n * 256 + c]
                      : f2b(goal[(size_t)n * 512 + (c - 256)]);
    zc[idx] = v;
}

__global__ __launch_bounds__(256) void final_dot_kernel(
    const unsigned short* __restrict__ t,
    const float* __restrict__ Wd2,
    const float* __restrict__ bd2,
    float* __restrict__ pred)
{
    const int lane = threadIdx.x & 63;
    const int wid  = threadIdx.x >> 6;
    float w[8];
#pragma unroll
    for (int i = 0; i < 8; i++) w[i] = Wd2[lane * 8 + i];
    const float bd = bd2[0];
    for (int n = blockIdx.x * 4 + wid; n < NNODES; n += gridDim.x * 4) {
        const unsigned short* tp = t + (size_t)n * 512 + lane * 8;
        float s = 0.f;
#pragma unroll
        for (int i = 0; i < 8; i++) s = fmaf(b2f(tp[i]), w[i], s);
#pragma unroll
        for (int off = 32; off; off >>= 1) s += __shfl_xor(s, off, 64);
        if (lane == 0) pred[n] = s + bd;
    }
}

// ---------------- launcher ----------------
extern "C" void kernel_launch(void* const* d_in, const int* in_sizes, int n_in,
                              void* d_out, int out_size, void* d_ws, size_t ws_size,
                              hipStream_t stream)
{
    (void)in_sizes; (void)n_in; (void)out_size; (void)ws_size;
    const float* x    = (const float*)d_in[0];
    const int*   ei   = (const int*)d_in[1];
    const float* ea   = (const float*)d_in[2];
    const float* goal = (const float*)d_in[3];
    const float* Wf1  = (const float*)d_in[4];
    const float* bf1  = (const float*)d_in[5];
    const float* Ws1  = (const float*)d_in[6];
    const float* bs1  = (const float*)d_in[7];
    const float* g1   = (const float*)d_in[8];
    const float* be1  = (const float*)d_in[9];
    const float* Wf2  = (const float*)d_in[10];
    const float* bf2  = (const float*)d_in[11];
    const float* Ws2  = (const float*)d_in[12];
    const float* bs2  = (const float*)d_in[13];
    const float* g2   = (const float*)d_in[14];
    const float* be2  = (const float*)d_in[15];
    const float* W3   = (const float*)d_in[16];
    const float* b3   = (const float*)d_in[17];
    const float* W4   = (const float*)d_in[18];
    const float* b4   = (const float*)d_in[19];
    const float* Wd1  = (const float*)d_in[20];
    const float* bd1  = (const float*)d_in[21];
    const float* Wd2  = (const float*)d_in[22];
    const float* bd2  = (const float*)d_in[23];
    float* outp = (float*)d_out;   // fp32: [0..N) pred, [N..N+N*256) h

    char* ws = (char*)d_ws;
    size_t off = 0;
    auto alloc = [&](size_t bytes) -> char* {
        char* p = ws + off;
        off += (bytes + 255) & ~(size_t)255;
        return p;
    };
    unsigned short* P     = (unsigned short*)alloc((size_t)NPAD * 2048 * 2); // later zc + tb
    unsigned short* bufA  = (unsigned short*)alloc((size_t)NPAD * 512 * 2);  // xpad / h2 / h4
    unsigned short* bufB  = (unsigned short*)alloc((size_t)NPAD * 512 * 2);  // h1 / pre_b
    unsigned short* bufC  = (unsigned short*)alloc((size_t)NPAD * 512 * 2);  // h3
    unsigned short* wpack = (unsigned short*)alloc((size_t)2048 * 512 * 2);
    int*            counts  = (int*)alloc((size_t)NNODES * 4);
    int*            row_ptr = (int*)alloc((size_t)(NNODES + 1) * 4);
    int*            csr_src = (int*)alloc((size_t)NEDGES * 4);
    int*            csr_eid = (int*)alloc((size_t)NEDGES * 4);
    float*          dinv    = (float*)alloc((size_t)NNODES * 4);
    unsigned int*   wEbuf   = (unsigned int*)alloc((size_t)8192 * 4);
    unsigned int*   eapk    = (unsigned int*)alloc((size_t)NEDGES * 8 * 4);

    unsigned short* xpad  = bufA;
    unsigned short* h1    = bufB;
    unsigned short* h2    = bufA;
    unsigned short* pre_b = bufB;
    unsigned short* h3    = bufC;
    unsigned short* h4    = bufA;
    unsigned short* zc    = P;
    unsigned short* tb    = P + (size_t)NPAD * 1024;

    const int B = 256;

    // ---- CSR build (by destination) + dinv ----
    hipMemsetAsync(counts, 0, (size_t)NNODES * 4, stream);
    count_kernel<<<(NEDGES + B - 1) / B, B, 0, stream>>>(ei, counts);
    scan_kernel<<<1, 1024, 0, stream>>>(counts, row_ptr);
    hipMemsetAsync(counts, 0, (size_t)NNODES * 4, stream);
    fill_kernel<<<(NEDGES + B - 1) / B, B, 0, stream>>>(ei, row_ptr, counts, csr_src, csr_eid);
    dinv_kernel<<<(NNODES + B - 1) / B, B, 0, stream>>>(row_ptr, dinv);
    pack_ea_kernel<<<(NEDGES * 8 + B - 1) / B, B, 0, stream>>>(csr_eid, ea, eapk);

    {
        long tot = (long)NPAD * 512;
        pad_copy_kernel<<<(unsigned)((tot + B - 1) / B), B, 0, stream>>>(x, xpad, NNODES, 512, tot);
    }

    dim3 gBig(NPAD / 128, 2048 / 128);

    // ---- CGConv layer 1 ----
    pack_cgw_kernel<<<(2048 * 512 + B - 1) / B, B, 0, stream>>>(Wf1, Ws1, wpack);
    pack_we_kernel<<<(8192 + B - 1) / B, B, 0, stream>>>(Wf1, Ws1, wEbuf);
    gemm_bt_kernel<<<gBig, B, 0, stream>>>(xpad, wpack, nullptr, P, NPAD, 2048, 512, nullptr);
    cg_gather_kernel<<<NPAD / CG_NPB, B, 0, stream>>>(P, row_ptr, csr_src,
                                                      (const u32x4*)wEbuf, (const u32x4*)eapk,
                                                      bf1, bs1, g1, be1,
                                                      x, nullptr, h1);

    // ---- CGConv layer 2 ----
    pack_cgw_kernel<<<(2048 * 512 + B - 1) / B, B, 0, stream>>>(Wf2, Ws2, wpack);
    gemm_bt_kernel<<<gBig, B, 0, stream>>>(h1, wpack, nullptr, P, NPAD, 2048, 512, nullptr);
    pack_we_kernel<<<(8192 + B - 1) / B, B, 0, stream>>>(Wf2, Ws2, wEbuf);
    cg_gather_kernel<<<NPAD / CG_NPB, B, 0, stream>>>(P, row_ptr, csr_src,
                                                      (const u32x4*)wEbuf, (const u32x4*)eapk,
                                                      bf2, bs2, g2, be2,
                                                      nullptr, h1, h2);

    // ---- GCN layer 3 ----
    pack_t_kernel<<<(256 * 512 + B - 1) / B, B, 0, stream>>>(W3, wpack, 512, 256);
    gemm_bt_kernel<<<dim3(NPAD / 128, 2), B, 0, stream>>>(h2, wpack, nullptr, pre_b, NPAD, 256, 512, nullptr);
    gcn_gather_kernel<<<NPAD / 2, B, 0, stream>>>(pre_b, row_ptr, csr_src, dinv, b3, h3, (float*)nullptr);

    // ---- GCN layer 4 ----
    pack_t_kernel<<<(256 * 256 + B - 1) / B, B, 0, stream>>>(W4, wpack, 256, 256);
    gemm_bt_kernel<<<dim3(NPAD / 128, 2), B, 0, stream>>>(h3, wpack, nullptr, pre_b, NPAD, 256, 256, nullptr);
    gcn_gather_kernel<<<NPAD / 2, B, 0, stream>>>(pre_b, row_ptr, csr_src, dinv, b4, h4, outp + NNODES);

    // ---- distance MLP (bias+ReLU fused into GEMM epilogue) ----
    build_zc_kernel<<<(unsigned)(((long)NPAD * 768 + B - 1) / B), B, 0, stream>>>(h4, goal, zc);
    pack_t_kernel<<<(512 * 768 + B - 1) / B, B, 0, stream>>>(Wd1, wpack, 768, 512);
    gemm_bt_kernel<<<dim3(NPAD / 128, 4), B, 0, stream>>>(zc, wpack, nullptr, tb, NPAD, 512, 768, bd1);
    final_dot_kernel<<<512, B, 0, stream>>>(tb, Wd2, bd2, outp);
}